// Round 6
// baseline (93.670 us; speedup 1.0000x reference)
//
#include <hip/hip_runtime.h>

// PointPillars voxelization, MI355X. Output FLOAT32 flat concat:
//   voxels [40000][32][8], coords [40000][3] (z,y,x), num_points [40000].
// Input float32 [N][8].
//
// Pipeline (validated across rounds; deterministic): per-voxel histogram ->
// occupancy prefix scan -> first 40000 occupied vids (ascending) get ranks ->
// append point indices into the head of each output row (int slots,
// overwritten by emit) -> emit sorts slots (stable original order), writes
// first 32 points + zero pad.
//
// THIS ROUND (binning experiment D): f32 multiply-by-reciprocal, matching
// XLA's div-by-constant -> mul-by-reciprocal rewrite: RN_f32(1/0.16f)=6.25f
// exactly, 1/4=0.25f. cx=floor(x*6.25f), cy=floor((y+39.68f)*6.25f),
// cz=floor((z+3f)*0.25f). Prior: f32-div 63.75 / f64-exact 56.25 /
// f64-f32consts 38.25 — all isolated boundary-point moves, structure clean.

constexpr int NXv = 432;
constexpr int NYv = 496;
constexpr int NZv = 1;
constexpr int NVOX = NXv * NYv * NZv;      // 214272
constexpr int MAX_PTSv = 32;
constexpr int MAX_VOXv = 40000;
constexpr int SLOT_CAP = 64;               // 64 ints = 256B, row = 1024B
constexpr int SCAN_BS = 256;
constexpr int NBLK = NVOX / SCAN_BS;       // 837 exact

constexpr size_t VOX_F   = (size_t)MAX_VOXv * MAX_PTSv * 8;  // 10,240,000 f32
constexpr size_t COORD_F = (size_t)MAX_VOXv * 3;             // 120,000 f32

__device__ __forceinline__ int voxel_id(float x, float y, float z) {
    // XLA-style: (v - lo) * (1/vs), all f32 RN. No FMA shape (add-then-mul).
    float fx = x * 6.25f;                  // (x - 0.0f) * RN(1/0.16f)
    float fy = (y + 39.68f) * 6.25f;
    float fz = (z + 3.0f) * 0.25f;
    int cx = (int)floorf(fx);
    int cy = (int)floorf(fy);
    int cz = (int)floorf(fz);
    if (cx < 0 || cx >= NXv || cy < 0 || cy >= NYv || cz < 0 || cz >= NZv)
        return -1;
    return (cz * NYv + cy) * NXv + cx;
}

__global__ void k_zero(unsigned int* p, int n) {
    int i = blockIdx.x * blockDim.x + threadIdx.x;
    int stride = gridDim.x * blockDim.x;
    for (; i < n; i += stride) p[i] = 0u;
}

__global__ void k_count(const float* __restrict__ pf, int N,
                        unsigned int* __restrict__ counts) {
    int i = blockIdx.x * blockDim.x + threadIdx.x;
    if (i >= N) return;
    float4 v = reinterpret_cast<const float4*>(pf)[(size_t)i * 2];
    int vid = voxel_id(v.x, v.y, v.z);
    if (vid >= 0) atomicAdd(&counts[vid], 1u);
}

__global__ void k_blocksum(const unsigned int* __restrict__ counts,
                           unsigned int* __restrict__ bsums) {
    int i = blockIdx.x * SCAN_BS + threadIdx.x;
    int flag = (counts[i] != 0u) ? 1 : 0;
    unsigned long long b = __ballot(flag);
    __shared__ unsigned int wsum[SCAN_BS / 64];
    if ((threadIdx.x & 63) == 0) wsum[threadIdx.x >> 6] = (unsigned)__popcll(b);
    __syncthreads();
    if (threadIdx.x == 0) {
        unsigned s = 0;
        for (int w = 0; w < SCAN_BS / 64; ++w) s += wsum[w];
        bsums[blockIdx.x] = s;
    }
}

__global__ void k_scan_bsums(unsigned int* __restrict__ bsums,
                             unsigned int* __restrict__ scal) {
    __shared__ unsigned int sh[1024];
    int t = threadIdx.x;
    unsigned v = (t < NBLK) ? bsums[t] : 0u;
    sh[t] = v;
    __syncthreads();
    for (int off = 1; off < 1024; off <<= 1) {
        unsigned add = (t >= off) ? sh[t - off] : 0u;
        __syncthreads();
        sh[t] += add;
        __syncthreads();
    }
    if (t < NBLK) bsums[t] = sh[t] - v;        // exclusive offset
    if (t == NBLK - 1) scal[0] = sh[t];        // total occupied voxels
}

__global__ void k_ranks(const unsigned int* __restrict__ counts,
                        const unsigned int* __restrict__ bsums,
                        int* __restrict__ rank_of, int* __restrict__ vid_of_rank) {
    int i = blockIdx.x * SCAN_BS + threadIdx.x;
    int t = threadIdx.x;
    int flag = (counts[i] != 0u) ? 1 : 0;
    __shared__ unsigned int sh[SCAN_BS];
    sh[t] = (unsigned)flag;
    __syncthreads();
    for (int off = 1; off < SCAN_BS; off <<= 1) {
        unsigned add = (t >= off) ? sh[t - off] : 0u;
        __syncthreads();
        sh[t] += add;
        __syncthreads();
    }
    unsigned rank = bsums[blockIdx.x] + sh[t] - (unsigned)flag;
    int r = (flag && rank < (unsigned)MAX_VOXv) ? (int)rank : -1;
    rank_of[i] = r;
    if (r >= 0) vid_of_rank[r] = i;
}

// append point index i into the int-slot head of f32 output row r
__global__ void k_append(const float* __restrict__ pf, int N,
                         const int* __restrict__ rank_of,
                         unsigned int* __restrict__ appcnt,
                         float* __restrict__ out) {
    int i = blockIdx.x * blockDim.x + threadIdx.x;
    if (i >= N) return;
    float4 v = reinterpret_cast<const float4*>(pf)[(size_t)i * 2];
    int vid = voxel_id(v.x, v.y, v.z);
    if (vid < 0) return;
    int r = rank_of[vid];
    if (r < 0) return;
    unsigned s = atomicAdd(&appcnt[r], 1u);
    if (s < (unsigned)SLOT_CAP) {
        int* rowi = reinterpret_cast<int*>(out + (size_t)r * (MAX_PTSv * 8));
        rowi[s] = i;                           // first 256B of the 1024B row
    }
}

// one 64-thread block per voxel row; rewrites the ENTIRE row + coords + num
__global__ void k_emit(const float* __restrict__ pf,
                       const unsigned int* __restrict__ appcnt,
                       const int* __restrict__ vid_of_rank,
                       const unsigned int* __restrict__ scal,
                       float* __restrict__ out) {
    int r = blockIdx.x;
    int t = threadIdx.x;
    float* row       = out + (size_t)r * (MAX_PTSv * 8);  // 256 f32 = 1024B
    float* out_coord = out + VOX_F;
    float* out_num   = out + VOX_F + COORD_F;
    unsigned K = min(scal[0], (unsigned)MAX_VOXv);

    if ((unsigned)r >= K) {
        reinterpret_cast<float4*>(row)[t] = make_float4(0.f, 0.f, 0.f, 0.f);
        if (t == 0) {
            out_coord[(size_t)r * 3 + 0] = 0.f;
            out_coord[(size_t)r * 3 + 1] = 0.f;
            out_coord[(size_t)r * 3 + 2] = 0.f;
            out_num[r] = 0.f;
        }
        return;
    }

    __shared__ int sidx[SLOT_CAP];
    int c = (int)min(appcnt[r], (unsigned)SLOT_CAP);
    const int* rowi = reinterpret_cast<const int*>(row);
    sidx[t] = (t < c) ? rowi[t] : 0x7fffffff;
    __syncthreads();                 // all slot reads done before row rewrite
    int nkeep = c < MAX_PTSv ? c : MAX_PTSv;

    if (t < c) {
        int my = sidx[t];
        int pos = 0;
        for (int j = 0; j < c; ++j) pos += (sidx[j] < my) ? 1 : 0;
        if (pos < MAX_PTSv) {
            const float4* src = reinterpret_cast<const float4*>(pf) + (size_t)my * 2;
            float4 a = src[0];
            float4 b = src[1];
            float4* dst = reinterpret_cast<float4*>(row + pos * 8);
            dst[0] = a;
            dst[1] = b;
        }
    }
    if (t >= nkeep && t < MAX_PTSv) {           // zero unused point slots
        float4* dst = reinterpret_cast<float4*>(row + t * 8);
        dst[0] = make_float4(0.f, 0.f, 0.f, 0.f);
        dst[1] = make_float4(0.f, 0.f, 0.f, 0.f);
    }
    if (t == 0) {
        int vid = vid_of_rank[r];
        int vx = vid % NXv;
        int vy = (vid / NXv) % NYv;
        int vz = vid / (NXv * NYv);
        out_coord[(size_t)r * 3 + 0] = (float)vz;
        out_coord[(size_t)r * 3 + 1] = (float)vy;
        out_coord[(size_t)r * 3 + 2] = (float)vx;
        out_num[r] = (float)nkeep;
    }
}

extern "C" void kernel_launch(void* const* d_in, const int* in_sizes, int n_in,
                              void* d_out, int out_size, void* d_ws, size_t ws_size,
                              hipStream_t stream) {
    const float* pf = (const float*)d_in[0];
    const int N = in_sizes[0] / 8;
    float* out = (float*)d_out;

    // ws (u32): [counts NVOX][appcnt MAX_VOX][bsums 1024][scal 4] <- zeroed
    //           [rank_of NVOX][vid_of_rank MAX_VOX]     total ~2.04 MB
    unsigned int* wsp         = (unsigned int*)d_ws;
    unsigned int* counts      = wsp;
    unsigned int* appcnt      = counts + NVOX;
    unsigned int* bsums       = appcnt + MAX_VOXv;
    unsigned int* scal        = bsums + 1024;
    int*          rank_of     = (int*)(scal + 4);
    int*          vid_of_rank = rank_of + NVOX;

    const int n_zero = NVOX + MAX_VOXv + 1024 + 4;
    k_zero<<<512, 256, 0, stream>>>(wsp, n_zero);

    k_count<<<(N + 255) / 256, 256, 0, stream>>>(pf, N, counts);
    k_blocksum<<<NBLK, SCAN_BS, 0, stream>>>(counts, bsums);
    k_scan_bsums<<<1, 1024, 0, stream>>>(bsums, scal);
    k_ranks<<<NBLK, SCAN_BS, 0, stream>>>(counts, bsums, rank_of, vid_of_rank);
    k_append<<<(N + 255) / 256, 256, 0, stream>>>(pf, N, rank_of, appcnt, out);
    k_emit<<<MAX_VOXv, 64, 0, stream>>>(pf, appcnt, vid_of_rank, scal, out);
}

// Round 7
// 55.435 us; speedup vs baseline: 1.6897x; 1.6897x over previous
//
#include <hip/hip_runtime.h>

// PointPillars voxelization, MI355X. Output FLOAT32 flat concat:
//   voxels [40000][32][8], coords [40000][3] (z,y,x), num_points [40000].
// Input float32 [N][8]. PASSED r6 (absmax 0) with binning:
//   cx=floor(x*6.25f), cy=floor((y+39.68f)*6.25f), cz=floor((z+3.f)*0.25f)
// (XLA div-by-const -> mul-by-reciprocal, f32 RN). DO NOT CHANGE BINNING.
//
// r7: merge the two point passes. k_prep stores vid per point + occupancy
// byte via PLAIN store (no atomic RMW); k_append2 reads vids (4.8MB) instead
// of re-reading points (38.4MB). Guarded by ws_size; falls back to the r6
// proven two-pass path if ws is too small.

constexpr int NXv = 432;
constexpr int NYv = 496;
constexpr int NZv = 1;
constexpr int NVOX = NXv * NYv * NZv;      // 214272
constexpr int MAX_PTSv = 32;
constexpr int MAX_VOXv = 40000;
constexpr int SLOT_CAP = 64;               // 64 ints = 256B, row = 1024B
constexpr int SCAN_BS = 256;
constexpr int NBLK = NVOX / SCAN_BS;       // 837 exact

constexpr size_t VOX_F   = (size_t)MAX_VOXv * MAX_PTSv * 8;  // 10,240,000 f32
constexpr size_t COORD_F = (size_t)MAX_VOXv * 3;             // 120,000 f32

__device__ __forceinline__ int voxel_id(float x, float y, float z) {
    float fx = x * 6.25f;
    float fy = (y + 39.68f) * 6.25f;
    float fz = (z + 3.0f) * 0.25f;
    int cx = (int)floorf(fx);
    int cy = (int)floorf(fy);
    int cz = (int)floorf(fz);
    if (cx < 0 || cx >= NXv || cy < 0 || cy >= NYv || cz < 0 || cz >= NZv)
        return -1;
    return (cz * NYv + cy) * NXv + cx;
}

__global__ void k_zero(unsigned int* p, int n) {
    int i = blockIdx.x * blockDim.x + threadIdx.x;
    int stride = gridDim.x * blockDim.x;
    for (; i < n; i += stride) p[i] = 0u;
}

// ---------- fast path (ws >= NEED): one point pass + vid replay ----------

__global__ void k_prep(const float* __restrict__ pf, int N,
                       int* __restrict__ vids, unsigned char* __restrict__ occ) {
    int i = blockIdx.x * blockDim.x + threadIdx.x;
    if (i >= N) return;
    float4 v = reinterpret_cast<const float4*>(pf)[(size_t)i * 2];
    int vid = voxel_id(v.x, v.y, v.z);
    vids[i] = vid;
    if (vid >= 0) occ[vid] = 1;          // plain byte store, no RMW
}

__global__ void k_blocksum2(const unsigned char* __restrict__ occ,
                            unsigned int* __restrict__ bsums) {
    int i = blockIdx.x * SCAN_BS + threadIdx.x;
    int flag = (occ[i] != 0) ? 1 : 0;
    unsigned long long b = __ballot(flag);
    __shared__ unsigned int wsum[SCAN_BS / 64];
    if ((threadIdx.x & 63) == 0) wsum[threadIdx.x >> 6] = (unsigned)__popcll(b);
    __syncthreads();
    if (threadIdx.x == 0) {
        unsigned s = 0;
        for (int w = 0; w < SCAN_BS / 64; ++w) s += wsum[w];
        bsums[blockIdx.x] = s;
    }
}

__global__ void k_ranks2(const unsigned char* __restrict__ occ,
                         const unsigned int* __restrict__ bsums,
                         int* __restrict__ rank_of, int* __restrict__ vid_of_rank) {
    int i = blockIdx.x * SCAN_BS + threadIdx.x;
    int t = threadIdx.x;
    int flag = (occ[i] != 0) ? 1 : 0;
    __shared__ unsigned int sh[SCAN_BS];
    sh[t] = (unsigned)flag;
    __syncthreads();
    for (int off = 1; off < SCAN_BS; off <<= 1) {
        unsigned add = (t >= off) ? sh[t - off] : 0u;
        __syncthreads();
        sh[t] += add;
        __syncthreads();
    }
    unsigned rank = bsums[blockIdx.x] + sh[t] - (unsigned)flag;
    int r = (flag && rank < (unsigned)MAX_VOXv) ? (int)rank : -1;
    rank_of[i] = r;
    if (r >= 0) vid_of_rank[r] = i;
}

__global__ void k_append2(const int* __restrict__ vids, int N,
                          const int* __restrict__ rank_of,
                          unsigned int* __restrict__ appcnt,
                          float* __restrict__ out) {
    int i = blockIdx.x * blockDim.x + threadIdx.x;
    if (i >= N) return;
    int vid = vids[i];
    if (vid < 0) return;
    int r = rank_of[vid];
    if (r < 0) return;
    unsigned s = atomicAdd(&appcnt[r], 1u);
    if (s < (unsigned)SLOT_CAP) {
        int* rowi = reinterpret_cast<int*>(out + (size_t)r * (MAX_PTSv * 8));
        rowi[s] = i;
    }
}

// ---------- fallback path (r6 proven): two passes over points ----------

__global__ void k_count(const float* __restrict__ pf, int N,
                        unsigned int* __restrict__ counts) {
    int i = blockIdx.x * blockDim.x + threadIdx.x;
    if (i >= N) return;
    float4 v = reinterpret_cast<const float4*>(pf)[(size_t)i * 2];
    int vid = voxel_id(v.x, v.y, v.z);
    if (vid >= 0) atomicAdd(&counts[vid], 1u);
}

__global__ void k_blocksum(const unsigned int* __restrict__ counts,
                           unsigned int* __restrict__ bsums) {
    int i = blockIdx.x * SCAN_BS + threadIdx.x;
    int flag = (counts[i] != 0u) ? 1 : 0;
    unsigned long long b = __ballot(flag);
    __shared__ unsigned int wsum[SCAN_BS / 64];
    if ((threadIdx.x & 63) == 0) wsum[threadIdx.x >> 6] = (unsigned)__popcll(b);
    __syncthreads();
    if (threadIdx.x == 0) {
        unsigned s = 0;
        for (int w = 0; w < SCAN_BS / 64; ++w) s += wsum[w];
        bsums[blockIdx.x] = s;
    }
}

__global__ void k_ranks(const unsigned int* __restrict__ counts,
                        const unsigned int* __restrict__ bsums,
                        int* __restrict__ rank_of, int* __restrict__ vid_of_rank) {
    int i = blockIdx.x * SCAN_BS + threadIdx.x;
    int t = threadIdx.x;
    int flag = (counts[i] != 0u) ? 1 : 0;
    __shared__ unsigned int sh[SCAN_BS];
    sh[t] = (unsigned)flag;
    __syncthreads();
    for (int off = 1; off < SCAN_BS; off <<= 1) {
        unsigned add = (t >= off) ? sh[t - off] : 0u;
        __syncthreads();
        sh[t] += add;
        __syncthreads();
    }
    unsigned rank = bsums[blockIdx.x] + sh[t] - (unsigned)flag;
    int r = (flag && rank < (unsigned)MAX_VOXv) ? (int)rank : -1;
    rank_of[i] = r;
    if (r >= 0) vid_of_rank[r] = i;
}

__global__ void k_append(const float* __restrict__ pf, int N,
                         const int* __restrict__ rank_of,
                         unsigned int* __restrict__ appcnt,
                         float* __restrict__ out) {
    int i = blockIdx.x * blockDim.x + threadIdx.x;
    if (i >= N) return;
    float4 v = reinterpret_cast<const float4*>(pf)[(size_t)i * 2];
    int vid = voxel_id(v.x, v.y, v.z);
    if (vid < 0) return;
    int r = rank_of[vid];
    if (r < 0) return;
    unsigned s = atomicAdd(&appcnt[r], 1u);
    if (s < (unsigned)SLOT_CAP) {
        int* rowi = reinterpret_cast<int*>(out + (size_t)r * (MAX_PTSv * 8));
        rowi[s] = i;
    }
}

// ---------- shared scan-of-block-sums + emit ----------

__global__ void k_scan_bsums(unsigned int* __restrict__ bsums,
                             unsigned int* __restrict__ scal) {
    __shared__ unsigned int sh[1024];
    int t = threadIdx.x;
    unsigned v = (t < NBLK) ? bsums[t] : 0u;
    sh[t] = v;
    __syncthreads();
    for (int off = 1; off < 1024; off <<= 1) {
        unsigned add = (t >= off) ? sh[t - off] : 0u;
        __syncthreads();
        sh[t] += add;
        __syncthreads();
    }
    if (t < NBLK) bsums[t] = sh[t] - v;
    if (t == NBLK - 1) scal[0] = sh[t];
}

__global__ void k_emit(const float* __restrict__ pf,
                       const unsigned int* __restrict__ appcnt,
                       const int* __restrict__ vid_of_rank,
                       const unsigned int* __restrict__ scal,
                       float* __restrict__ out) {
    int r = blockIdx.x;
    int t = threadIdx.x;
    float* row       = out + (size_t)r * (MAX_PTSv * 8);
    float* out_coord = out + VOX_F;
    float* out_num   = out + VOX_F + COORD_F;
    unsigned K = min(scal[0], (unsigned)MAX_VOXv);

    if ((unsigned)r >= K) {
        reinterpret_cast<float4*>(row)[t] = make_float4(0.f, 0.f, 0.f, 0.f);
        if (t == 0) {
            out_coord[(size_t)r * 3 + 0] = 0.f;
            out_coord[(size_t)r * 3 + 1] = 0.f;
            out_coord[(size_t)r * 3 + 2] = 0.f;
            out_num[r] = 0.f;
        }
        return;
    }

    __shared__ int sidx[SLOT_CAP];
    int c = (int)min(appcnt[r], (unsigned)SLOT_CAP);
    const int* rowi = reinterpret_cast<const int*>(row);
    sidx[t] = (t < c) ? rowi[t] : 0x7fffffff;
    __syncthreads();
    int nkeep = c < MAX_PTSv ? c : MAX_PTSv;

    if (t < c) {
        int my = sidx[t];
        int pos = 0;
        for (int j = 0; j < c; ++j) pos += (sidx[j] < my) ? 1 : 0;
        if (pos < MAX_PTSv) {
            const float4* src = reinterpret_cast<const float4*>(pf) + (size_t)my * 2;
            float4 a = src[0];
            float4 b = src[1];
            float4* dst = reinterpret_cast<float4*>(row + pos * 8);
            dst[0] = a;
            dst[1] = b;
        }
    }
    if (t >= nkeep && t < MAX_PTSv) {
        float4* dst = reinterpret_cast<float4*>(row + t * 8);
        dst[0] = make_float4(0.f, 0.f, 0.f, 0.f);
        dst[1] = make_float4(0.f, 0.f, 0.f, 0.f);
    }
    if (t == 0) {
        int vid = vid_of_rank[r];
        int vx = vid % NXv;
        int vy = (vid / NXv) % NYv;
        int vz = vid / (NXv * NYv);
        out_coord[(size_t)r * 3 + 0] = (float)vz;
        out_coord[(size_t)r * 3 + 1] = (float)vy;
        out_coord[(size_t)r * 3 + 2] = (float)vx;
        out_num[r] = (float)nkeep;
    }
}

extern "C" void kernel_launch(void* const* d_in, const int* in_sizes, int n_in,
                              void* d_out, int out_size, void* d_ws, size_t ws_size,
                              hipStream_t stream) {
    const float* pf = (const float*)d_in[0];
    const int N = in_sizes[0] / 8;
    float* out = (float*)d_out;

    // fast-path ws layout (bytes):
    //   [occ u8 NVOX pad->215040][appcnt u32 160000][bsums 4096][scal 16]  zeroed
    //   [rank_of i32 857088][vid_of_rank i32 160000][vids i32 N*4]
    const size_t OCC_B   = 215040;               // NVOX=214272 padded
    const size_t APP_B   = (size_t)MAX_VOXv * 4; // 160000
    const size_t BS_B    = 4096;
    const size_t SCAL_B  = 16;
    const size_t ZERO_B  = OCC_B + APP_B + BS_B + SCAL_B;          // 379152
    const size_t RANK_B  = (size_t)NVOX * 4;                       // 857088
    const size_t VOR_B   = (size_t)MAX_VOXv * 4;                   // 160000
    const size_t NEED    = ZERO_B + RANK_B + VOR_B + (size_t)N * 4;

    char* wsb = (char*)d_ws;
    unsigned char* occ        = (unsigned char*)wsb;
    unsigned int* appcnt      = (unsigned int*)(wsb + OCC_B);
    unsigned int* bsums       = (unsigned int*)(wsb + OCC_B + APP_B);
    unsigned int* scal        = (unsigned int*)(wsb + OCC_B + APP_B + BS_B);
    int*          rank_of     = (int*)(wsb + ZERO_B);
    int*          vid_of_rank = (int*)(wsb + ZERO_B + RANK_B);
    int*          vids        = (int*)(wsb + ZERO_B + RANK_B + VOR_B);

    if (ws_size >= NEED) {
        k_zero<<<512, 256, 0, stream>>>((unsigned int*)wsb, (int)(ZERO_B / 4));
        k_prep<<<(N + 255) / 256, 256, 0, stream>>>(pf, N, vids, occ);
        k_blocksum2<<<NBLK, SCAN_BS, 0, stream>>>(occ, bsums);
        k_scan_bsums<<<1, 1024, 0, stream>>>(bsums, scal);
        k_ranks2<<<NBLK, SCAN_BS, 0, stream>>>(occ, bsums, rank_of, vid_of_rank);
        k_append2<<<(N + 255) / 256, 256, 0, stream>>>(vids, N, rank_of, appcnt, out);
        k_emit<<<MAX_VOXv, 64, 0, stream>>>(pf, appcnt, vid_of_rank, scal, out);
        return;
    }

    // fallback: r6 proven layout/path (~2.04 MB)
    unsigned int* wsp          = (unsigned int*)d_ws;
    unsigned int* counts_f     = wsp;
    unsigned int* appcnt_f     = counts_f + NVOX;
    unsigned int* bsums_f      = appcnt_f + MAX_VOXv;
    unsigned int* scal_f       = bsums_f + 1024;
    int*          rank_of_f    = (int*)(scal_f + 4);
    int*          vid_of_rk_f  = rank_of_f + NVOX;

    const int n_zero = NVOX + MAX_VOXv + 1024 + 4;
    k_zero<<<512, 256, 0, stream>>>(wsp, n_zero);
    k_count<<<(N + 255) / 256, 256, 0, stream>>>(pf, N, counts_f);
    k_blocksum<<<NBLK, SCAN_BS, 0, stream>>>(counts_f, bsums_f);
    k_scan_bsums<<<1, 1024, 0, stream>>>(bsums_f, scal_f);
    k_ranks<<<NBLK, SCAN_BS, 0, stream>>>(counts_f, bsums_f, rank_of_f, vid_of_rk_f);
    k_append<<<(N + 255) / 256, 256, 0, stream>>>(pf, N, rank_of_f, appcnt_f, out);
    k_emit<<<MAX_VOXv, 64, 0, stream>>>(pf, appcnt_f, vid_of_rk_f, scal_f, out);
}

// Round 8
// 55.306 us; speedup vs baseline: 1.6937x; 1.0023x over previous
//
#include <hip/hip_runtime.h>

// PointPillars voxelization, MI355X. Output FLOAT32 flat concat:
//   voxels [40000][32][8], coords [40000][3] (z,y,x), num_points [40000].
// Input float32 [N][8]. PASSED r6/r7 (absmax 0) with binning:
//   cx=floor(x*6.25f), cy=floor((y+39.68f)*6.25f), cz=floor((z+3.f)*0.25f)
// (XLA div-by-const -> mul-by-reciprocal, f32 RN). DO NOT CHANGE BINNING.
//
// r8 experiment: pad appcnt to one counter per 64B cache line (appcnt[r*16])
// to eliminate cross-XCD false sharing on the append atomics. ws = 256 MiB
// (measured from poison fills), so the 2.56 MB padded array is free.

constexpr int NXv = 432;
constexpr int NYv = 496;
constexpr int NZv = 1;
constexpr int NVOX = NXv * NYv * NZv;      // 214272
constexpr int MAX_PTSv = 32;
constexpr int MAX_VOXv = 40000;
constexpr int SLOT_CAP = 64;               // 64 ints = 256B, row = 1024B
constexpr int SCAN_BS = 256;
constexpr int NBLK = NVOX / SCAN_BS;       // 837 exact
constexpr int APP_STRIDE = 16;             // u32s per padded counter (64B)

constexpr size_t VOX_F   = (size_t)MAX_VOXv * MAX_PTSv * 8;  // 10,240,000 f32
constexpr size_t COORD_F = (size_t)MAX_VOXv * 3;             // 120,000 f32

__device__ __forceinline__ int voxel_id(float x, float y, float z) {
    float fx = x * 6.25f;
    float fy = (y + 39.68f) * 6.25f;
    float fz = (z + 3.0f) * 0.25f;
    int cx = (int)floorf(fx);
    int cy = (int)floorf(fy);
    int cz = (int)floorf(fz);
    if (cx < 0 || cx >= NXv || cy < 0 || cy >= NYv || cz < 0 || cz >= NZv)
        return -1;
    return (cz * NYv + cy) * NXv + cx;
}

__global__ void k_zero(unsigned int* p, int n) {
    int i = blockIdx.x * blockDim.x + threadIdx.x;
    int stride = gridDim.x * blockDim.x;
    for (; i < n; i += stride) p[i] = 0u;
}

// ---------- fast path: one point pass + vid replay ----------

__global__ void k_prep(const float* __restrict__ pf, int N,
                       int* __restrict__ vids, unsigned char* __restrict__ occ) {
    int i = blockIdx.x * blockDim.x + threadIdx.x;
    if (i >= N) return;
    float4 v = reinterpret_cast<const float4*>(pf)[(size_t)i * 2];
    int vid = voxel_id(v.x, v.y, v.z);
    vids[i] = vid;
    if (vid >= 0) occ[vid] = 1;          // plain byte store, no RMW
}

__global__ void k_blocksum2(const unsigned char* __restrict__ occ,
                            unsigned int* __restrict__ bsums) {
    int i = blockIdx.x * SCAN_BS + threadIdx.x;
    int flag = (occ[i] != 0) ? 1 : 0;
    unsigned long long b = __ballot(flag);
    __shared__ unsigned int wsum[SCAN_BS / 64];
    if ((threadIdx.x & 63) == 0) wsum[threadIdx.x >> 6] = (unsigned)__popcll(b);
    __syncthreads();
    if (threadIdx.x == 0) {
        unsigned s = 0;
        for (int w = 0; w < SCAN_BS / 64; ++w) s += wsum[w];
        bsums[blockIdx.x] = s;
    }
}

__global__ void k_ranks2(const unsigned char* __restrict__ occ,
                         const unsigned int* __restrict__ bsums,
                         int* __restrict__ rank_of, int* __restrict__ vid_of_rank) {
    int i = blockIdx.x * SCAN_BS + threadIdx.x;
    int t = threadIdx.x;
    int flag = (occ[i] != 0) ? 1 : 0;
    __shared__ unsigned int sh[SCAN_BS];
    sh[t] = (unsigned)flag;
    __syncthreads();
    for (int off = 1; off < SCAN_BS; off <<= 1) {
        unsigned add = (t >= off) ? sh[t - off] : 0u;
        __syncthreads();
        sh[t] += add;
        __syncthreads();
    }
    unsigned rank = bsums[blockIdx.x] + sh[t] - (unsigned)flag;
    int r = (flag && rank < (unsigned)MAX_VOXv) ? (int)rank : -1;
    rank_of[i] = r;
    if (r >= 0) vid_of_rank[r] = i;
}

__global__ void k_append2(const int* __restrict__ vids, int N,
                          const int* __restrict__ rank_of,
                          unsigned int* __restrict__ appcnt,   // padded x16
                          float* __restrict__ out) {
    int i = blockIdx.x * blockDim.x + threadIdx.x;
    if (i >= N) return;
    int vid = vids[i];
    if (vid < 0) return;
    int r = rank_of[vid];
    if (r < 0) return;
    unsigned s = atomicAdd(&appcnt[(size_t)r * APP_STRIDE], 1u);
    if (s < (unsigned)SLOT_CAP) {
        int* rowi = reinterpret_cast<int*>(out + (size_t)r * (MAX_PTSv * 8));
        rowi[s] = i;
    }
}

// ---------- fallback path (r6 proven): two passes over points ----------

__global__ void k_count(const float* __restrict__ pf, int N,
                        unsigned int* __restrict__ counts) {
    int i = blockIdx.x * blockDim.x + threadIdx.x;
    if (i >= N) return;
    float4 v = reinterpret_cast<const float4*>(pf)[(size_t)i * 2];
    int vid = voxel_id(v.x, v.y, v.z);
    if (vid >= 0) atomicAdd(&counts[vid], 1u);
}

__global__ void k_blocksum(const unsigned int* __restrict__ counts,
                           unsigned int* __restrict__ bsums) {
    int i = blockIdx.x * SCAN_BS + threadIdx.x;
    int flag = (counts[i] != 0u) ? 1 : 0;
    unsigned long long b = __ballot(flag);
    __shared__ unsigned int wsum[SCAN_BS / 64];
    if ((threadIdx.x & 63) == 0) wsum[threadIdx.x >> 6] = (unsigned)__popcll(b);
    __syncthreads();
    if (threadIdx.x == 0) {
        unsigned s = 0;
        for (int w = 0; w < SCAN_BS / 64; ++w) s += wsum[w];
        bsums[blockIdx.x] = s;
    }
}

__global__ void k_ranks(const unsigned int* __restrict__ counts,
                        const unsigned int* __restrict__ bsums,
                        int* __restrict__ rank_of, int* __restrict__ vid_of_rank) {
    int i = blockIdx.x * SCAN_BS + threadIdx.x;
    int t = threadIdx.x;
    int flag = (counts[i] != 0u) ? 1 : 0;
    __shared__ unsigned int sh[SCAN_BS];
    sh[t] = (unsigned)flag;
    __syncthreads();
    for (int off = 1; off < SCAN_BS; off <<= 1) {
        unsigned add = (t >= off) ? sh[t - off] : 0u;
        __syncthreads();
        sh[t] += add;
        __syncthreads();
    }
    unsigned rank = bsums[blockIdx.x] + sh[t] - (unsigned)flag;
    int r = (flag && rank < (unsigned)MAX_VOXv) ? (int)rank : -1;
    rank_of[i] = r;
    if (r >= 0) vid_of_rank[r] = i;
}

__global__ void k_append(const float* __restrict__ pf, int N,
                         const int* __restrict__ rank_of,
                         unsigned int* __restrict__ appcnt,   // unpadded
                         float* __restrict__ out) {
    int i = blockIdx.x * blockDim.x + threadIdx.x;
    if (i >= N) return;
    float4 v = reinterpret_cast<const float4*>(pf)[(size_t)i * 2];
    int vid = voxel_id(v.x, v.y, v.z);
    if (vid < 0) return;
    int r = rank_of[vid];
    if (r < 0) return;
    unsigned s = atomicAdd(&appcnt[r], 1u);
    if (s < (unsigned)SLOT_CAP) {
        int* rowi = reinterpret_cast<int*>(out + (size_t)r * (MAX_PTSv * 8));
        rowi[s] = i;
    }
}

// ---------- shared scan-of-block-sums + emit ----------

__global__ void k_scan_bsums(unsigned int* __restrict__ bsums,
                             unsigned int* __restrict__ scal) {
    __shared__ unsigned int sh[1024];
    int t = threadIdx.x;
    unsigned v = (t < NBLK) ? bsums[t] : 0u;
    sh[t] = v;
    __syncthreads();
    for (int off = 1; off < 1024; off <<= 1) {
        unsigned add = (t >= off) ? sh[t - off] : 0u;
        __syncthreads();
        sh[t] += add;
        __syncthreads();
    }
    if (t < NBLK) bsums[t] = sh[t] - v;
    if (t == NBLK - 1) scal[0] = sh[t];
}

template<int CSTRIDE>
__global__ void k_emit(const float* __restrict__ pf,
                       const unsigned int* __restrict__ appcnt,
                       const int* __restrict__ vid_of_rank,
                       const unsigned int* __restrict__ scal,
                       float* __restrict__ out) {
    int r = blockIdx.x;
    int t = threadIdx.x;
    float* row       = out + (size_t)r * (MAX_PTSv * 8);
    float* out_coord = out + VOX_F;
    float* out_num   = out + VOX_F + COORD_F;
    unsigned K = min(scal[0], (unsigned)MAX_VOXv);

    if ((unsigned)r >= K) {
        reinterpret_cast<float4*>(row)[t] = make_float4(0.f, 0.f, 0.f, 0.f);
        if (t == 0) {
            out_coord[(size_t)r * 3 + 0] = 0.f;
            out_coord[(size_t)r * 3 + 1] = 0.f;
            out_coord[(size_t)r * 3 + 2] = 0.f;
            out_num[r] = 0.f;
        }
        return;
    }

    __shared__ int sidx[SLOT_CAP];
    int c = (int)min(appcnt[(size_t)r * CSTRIDE], (unsigned)SLOT_CAP);
    const int* rowi = reinterpret_cast<const int*>(row);
    sidx[t] = (t < c) ? rowi[t] : 0x7fffffff;
    __syncthreads();
    int nkeep = c < MAX_PTSv ? c : MAX_PTSv;

    if (t < c) {
        int my = sidx[t];
        int pos = 0;
        for (int j = 0; j < c; ++j) pos += (sidx[j] < my) ? 1 : 0;
        if (pos < MAX_PTSv) {
            const float4* src = reinterpret_cast<const float4*>(pf) + (size_t)my * 2;
            float4 a = src[0];
            float4 b = src[1];
            float4* dst = reinterpret_cast<float4*>(row + pos * 8);
            dst[0] = a;
            dst[1] = b;
        }
    }
    if (t >= nkeep && t < MAX_PTSv) {
        float4* dst = reinterpret_cast<float4*>(row + t * 8);
        dst[0] = make_float4(0.f, 0.f, 0.f, 0.f);
        dst[1] = make_float4(0.f, 0.f, 0.f, 0.f);
    }
    if (t == 0) {
        int vid = vid_of_rank[r];
        int vx = vid % NXv;
        int vy = (vid / NXv) % NYv;
        int vz = vid / (NXv * NYv);
        out_coord[(size_t)r * 3 + 0] = (float)vz;
        out_coord[(size_t)r * 3 + 1] = (float)vy;
        out_coord[(size_t)r * 3 + 2] = (float)vx;
        out_num[r] = (float)nkeep;
    }
}

extern "C" void kernel_launch(void* const* d_in, const int* in_sizes, int n_in,
                              void* d_out, int out_size, void* d_ws, size_t ws_size,
                              hipStream_t stream) {
    const float* pf = (const float*)d_in[0];
    const int N = in_sizes[0] / 8;
    float* out = (float*)d_out;

    // fast-path ws layout (bytes), zero-region first:
    //   [occ u8 215040][bsums 4096][scal 64][appcnt_pad 40000*64]
    //   [rank_of i32 NVOX][vid_of_rank i32 MAX_VOX][vids i32 N]
    const size_t OCC_B   = 215040;                         // NVOX padded
    const size_t BS_B    = 4096;
    const size_t SCAL_B  = 64;
    const size_t APP_B   = (size_t)MAX_VOXv * 64;          // 2,560,000
    const size_t ZERO_B  = OCC_B + BS_B + SCAL_B + APP_B;  // 2,779,200
    const size_t RANK_B  = (size_t)NVOX * 4;               // 857,088
    const size_t VOR_B   = (size_t)MAX_VOXv * 4;           // 160,000
    const size_t NEED    = ZERO_B + RANK_B + VOR_B + (size_t)N * 4;

    char* wsb = (char*)d_ws;
    unsigned char* occ        = (unsigned char*)wsb;
    unsigned int* bsums       = (unsigned int*)(wsb + OCC_B);
    unsigned int* scal        = (unsigned int*)(wsb + OCC_B + BS_B);
    unsigned int* appcnt      = (unsigned int*)(wsb + OCC_B + BS_B + SCAL_B);
    int*          rank_of     = (int*)(wsb + ZERO_B);
    int*          vid_of_rank = (int*)(wsb + ZERO_B + RANK_B);
    int*          vids        = (int*)(wsb + ZERO_B + RANK_B + VOR_B);

    if (ws_size >= NEED) {
        k_zero<<<1024, 256, 0, stream>>>((unsigned int*)wsb, (int)(ZERO_B / 4));
        k_prep<<<(N + 255) / 256, 256, 0, stream>>>(pf, N, vids, occ);
        k_blocksum2<<<NBLK, SCAN_BS, 0, stream>>>(occ, bsums);
        k_scan_bsums<<<1, 1024, 0, stream>>>(bsums, scal);
        k_ranks2<<<NBLK, SCAN_BS, 0, stream>>>(occ, bsums, rank_of, vid_of_rank);
        k_append2<<<(N + 255) / 256, 256, 0, stream>>>(vids, N, rank_of, appcnt, out);
        k_emit<APP_STRIDE><<<MAX_VOXv, 64, 0, stream>>>(pf, appcnt, vid_of_rank, scal, out);
        return;
    }

    // fallback: r6 proven layout/path (~2.04 MB)
    unsigned int* wsp          = (unsigned int*)d_ws;
    unsigned int* counts_f     = wsp;
    unsigned int* appcnt_f     = counts_f + NVOX;
    unsigned int* bsums_f      = appcnt_f + MAX_VOXv;
    unsigned int* scal_f       = bsums_f + 1024;
    int*          rank_of_f    = (int*)(scal_f + 4);
    int*          vid_of_rk_f  = rank_of_f + NVOX;

    const int n_zero = NVOX + MAX_VOXv + 1024 + 4;
    k_zero<<<512, 256, 0, stream>>>(wsp, n_zero);
    k_count<<<(N + 255) / 256, 256, 0, stream>>>(pf, N, counts_f);
    k_blocksum<<<NBLK, SCAN_BS, 0, stream>>>(counts_f, bsums_f);
    k_scan_bsums<<<1, 1024, 0, stream>>>(bsums_f, scal_f);
    k_ranks<<<NBLK, SCAN_BS, 0, stream>>>(counts_f, bsums_f, rank_of_f, vid_of_rk_f);
    k_append<<<(N + 255) / 256, 256, 0, stream>>>(pf, N, rank_of_f, appcnt_f, out);
    k_emit<1><<<MAX_VOXv, 64, 0, stream>>>(pf, appcnt_f, vid_of_rk_f, scal_f, out);
}